// Round 4
// baseline (2688.654 us; speedup 1.0000x reference)
//
#include <hip/hip_runtime.h>
#include <hip/hip_bf16.h>
#include <math.h>

#define B_   2
#define S_   2048
#define HID_ 2048
#define NH_  32
#define NKV_ 8
#define D_   64
#define G_   (NH_/NKV_)

typedef __hip_bfloat16 bf16;
typedef short bf16x8 __attribute__((ext_vector_type(8)));
typedef float f32x4  __attribute__((ext_vector_type(4)));

__device__ inline float bflo(unsigned u){ return __uint_as_float(u << 16); }
__device__ inline float bfhi(unsigned u){ return __uint_as_float(u & 0xffff0000u); }
__device__ inline unsigned short f2bfu(float f){
    __hip_bfloat16 h = __float2bfloat16(f);
    return __builtin_bit_cast(unsigned short, h);
}
__device__ inline unsigned pack2(float lo, float hi){
    return (unsigned)f2bfu(lo) | ((unsigned)f2bfu(hi) << 16);
}

// ---------------------------------------------------------------------------
// MFMA GEMM, fp32 inputs converted to bf16 in-register, bf16 MFMA compute.
// A_MODE 0: A fp32 row-major [M,K]
// A_MODE 1: A bf16 gathered from [B, NH, S, D] (attention output), k = h*D+d
// C_MODE 1: C bf16 scattered to [B, HC, S, D], n = h*D+d
// C_MODE 0: C fp32 row-major [M,N] (the final output)
// W, bias always fp32. Block: 256 threads (4 waves), 64x64 tile, BK=64.
// ---------------------------------------------------------------------------
template<int A_MODE, int C_MODE>
__global__ __launch_bounds__(256) void gemm_k(
    const void* __restrict__ Ax, const float* __restrict__ W,
    const float* __restrict__ bias, void* __restrict__ Cx,
    int M, int N, int K, int HC)
{
    __shared__ unsigned short sA[64][72];  // [m][k], pad to 72
    __shared__ unsigned short sB[64][72];  // [n][k] (transposed W tile)

    const int tid  = threadIdx.x;
    const int m0   = blockIdx.y * 64;
    const int n0   = blockIdx.x * 64;
    const int wave = tid >> 6;
    const int lane = tid & 63;
    const int wm   = (wave >> 1) * 32;
    const int wn   = (wave & 1) * 32;
    const int lr   = lane & 15;
    const int lq   = lane >> 4;

    f32x4 acc[2][2];
    #pragma unroll
    for (int i = 0; i < 2; i++)
        #pragma unroll
        for (int j = 0; j < 2; j++)
            acc[i][j] = (f32x4){0.f, 0.f, 0.f, 0.f};

    const int ar = tid >> 2, ac = (tid & 3) * 16;   // A staging: row, col
    const int bk = tid >> 2, bn = (tid & 3) * 16;   // W staging: k-row, n-col

    for (int k0 = 0; k0 < K; k0 += 64) {
        // ---- global loads into regs (16 bf16 values each for A and W) ----
        union { uint4 q[2]; unsigned short u[16]; } av, wv;
        {
            const int m = m0 + ar;
            const int k = k0 + ac;
            if (A_MODE == 1) {
                const int b = m / S_, s = m % S_;
                const int h = k / D_, d = k % D_;   // 16 elems stay in one head row
                const bf16* src = (const bf16*)Ax +
                    ((((size_t)b * NH_ + h) * S_ + s) * D_ + d);
                av.q[0] = ((const uint4*)src)[0];
                av.q[1] = ((const uint4*)src)[1];
            } else {
                const float* src = (const float*)Ax + (size_t)m * K + k;
                const float4 f0 = ((const float4*)src)[0];
                const float4 f1 = ((const float4*)src)[1];
                const float4 f2 = ((const float4*)src)[2];
                const float4 f3 = ((const float4*)src)[3];
                av.q[0] = make_uint4(pack2(f0.x,f0.y), pack2(f0.z,f0.w),
                                     pack2(f1.x,f1.y), pack2(f1.z,f1.w));
                av.q[1] = make_uint4(pack2(f2.x,f2.y), pack2(f2.z,f2.w),
                                     pack2(f3.x,f3.y), pack2(f3.z,f3.w));
            }
        }
        {
            const float* src = W + (size_t)(k0 + bk) * N + n0 + bn;
            const float4 f0 = ((const float4*)src)[0];
            const float4 f1 = ((const float4*)src)[1];
            const float4 f2 = ((const float4*)src)[2];
            const float4 f3 = ((const float4*)src)[3];
            wv.q[0] = make_uint4(pack2(f0.x,f0.y), pack2(f0.z,f0.w),
                                 pack2(f1.x,f1.y), pack2(f1.z,f1.w));
            wv.q[1] = make_uint4(pack2(f2.x,f2.y), pack2(f2.z,f2.w),
                                 pack2(f3.x,f3.y), pack2(f3.z,f3.w));
        }

        __syncthreads();   // previous iter's LDS reads complete

        *(uint4*)&sA[ar][ac]     = av.q[0];
        *(uint4*)&sA[ar][ac + 8] = av.q[1];
        #pragma unroll
        for (int j = 0; j < 16; j++) sB[bn + j][bk] = wv.u[j];

        __syncthreads();

        #pragma unroll
        for (int ks = 0; ks < 64; ks += 32) {
            bf16x8 af[2], bfg[2];
            #pragma unroll
            for (int mt = 0; mt < 2; mt++)
                af[mt] = *(const bf16x8*)&sA[wm + mt * 16 + lr][ks + lq * 8];
            #pragma unroll
            for (int nt = 0; nt < 2; nt++)
                bfg[nt] = *(const bf16x8*)&sB[wn + nt * 16 + lr][ks + lq * 8];
            #pragma unroll
            for (int mt = 0; mt < 2; mt++)
                #pragma unroll
                for (int nt = 0; nt < 2; nt++)
                    acc[mt][nt] = __builtin_amdgcn_mfma_f32_16x16x32_bf16(
                        af[mt], bfg[nt], acc[mt][nt], 0, 0, 0);
        }
    }

    // ---- epilogue: bias + store (C/D layout: col=lane&15, row=(lane>>4)*4+r) ----
    #pragma unroll
    for (int mt = 0; mt < 2; mt++) {
        #pragma unroll
        for (int nt = 0; nt < 2; nt++) {
            #pragma unroll
            for (int r = 0; r < 4; r++) {
                const int row = m0 + wm + mt * 16 + lq * 4 + r;
                const int col = n0 + wn + nt * 16 + lr;
                const float v = acc[mt][nt][r] + bias[col];
                if (C_MODE == 0) {
                    ((float*)Cx)[(size_t)row * N + col] = v;
                } else {
                    const int b = row / S_, s = row % S_;
                    const int h = col / D_, d = col % D_;
                    ((bf16*)Cx)[(((size_t)b * HC + h) * S_ + s) * D_ + d] =
                        __float2bfloat16(v);
                }
            }
        }
    }
}

// ---------------------------------------------------------------------------
// RoPE cos/sin table (double precision). position_ids may be int32 or int64;
// distinguish via pos32[1] (arange: int32 -> 1, int64 -> 0).
// ---------------------------------------------------------------------------
__global__ __launch_bounds__(256) void rope_tab_k(
    const int* __restrict__ pos, float* __restrict__ ctab, float* __restrict__ stab)
{
    const int idx = blockIdx.x * 256 + threadIdx.x;
    if (idx >= S_ * 32) return;
    const int s = idx >> 5, i = idx & 31;
    const int is64 = (pos[1] == 0);
    const int p = is64 ? pos[2 * s] : pos[s];
    const double inv = exp(-(double)i * (log(150000.0) / 32.0));
    const double f = (double)p * inv;
    ctab[idx] = (float)cos(f);
    stab[idx] = (float)sin(f);
}

// ---------------------------------------------------------------------------
// Apply RoPE in place to q_ws [B,NH,S,D] and k_ws [B,NKV,S,D] (bf16).
// ---------------------------------------------------------------------------
__global__ __launch_bounds__(256) void rope_apply_k(
    bf16* __restrict__ q, bf16* __restrict__ k,
    const float* __restrict__ ctab, const float* __restrict__ stab)
{
    const int QP = B_ * NH_ * S_ * 32;
    const int KP = B_ * NKV_ * S_ * 32;
    const int idx = blockIdx.x * 256 + threadIdx.x;
    bf16* base; int rem;
    if (idx < QP)           { base = q; rem = idx; }
    else if (idx < QP + KP) { base = k; rem = idx - QP; }
    else return;
    const int row = rem >> 5, i = rem & 31;
    const int s = row & (S_ - 1);
    const float c  = ctab[s * 32 + i];
    const float sn = stab[s * 32 + i];
    bf16* p = base + (size_t)row * D_ + i;
    const float x1 = __bfloat162float(p[0]);
    const float x2 = __bfloat162float(p[32]);
    p[0]  = __float2bfloat16(x1 * c - x2 * sn);
    p[32] = __float2bfloat16(x2 * c + x1 * sn);
}

// ---------------------------------------------------------------------------
// Flash-style attention (NO causal mask), vector fp32. qws/ows alias
// (in-place): each block reads its own 256 Q rows into registers before
// writing exactly those rows. K/V are separate bf16 buffers.
// ---------------------------------------------------------------------------
__global__ __launch_bounds__(256) void attn_k(
    const bf16* qws, const bf16* __restrict__ kws,
    const bf16* __restrict__ vws, bf16* ows)
{
    __shared__ float sK[64][64];
    __shared__ float sV[64][64];

    const int tid  = threadIdx.x;
    const int bh   = blockIdx.y;              // b*NH + h
    const int wave = tid >> 6, lane = tid & 63;
    const int qrow = blockIdx.x * 256 + wave * 64 + lane;
    const int b    = bh / NH_, h = bh % NH_;
    const int kvb  = b * NKV_ + h / G_;

    float qv[64];
    {
        const uint4* qp = (const uint4*)(qws + ((size_t)bh * S_ + qrow) * D_);
        #pragma unroll
        for (int j = 0; j < 8; j++) {
            const uint4 u = qp[j];
            qv[j*8+0] = bflo(u.x) * 0.125f; qv[j*8+1] = bfhi(u.x) * 0.125f;
            qv[j*8+2] = bflo(u.y) * 0.125f; qv[j*8+3] = bfhi(u.y) * 0.125f;
            qv[j*8+4] = bflo(u.z) * 0.125f; qv[j*8+5] = bfhi(u.z) * 0.125f;
            qv[j*8+6] = bflo(u.w) * 0.125f; qv[j*8+7] = bfhi(u.w) * 0.125f;
        }
    }

    float acc[64];
    #pragma unroll
    for (int d = 0; d < 64; d++) acc[d] = 0.f;
    float mrun = -1e30f, lrun = 0.f;

    const int sr = tid >> 2, scol = (tid & 3) * 16;
    const bf16* kbase = kws + (size_t)kvb * S_ * D_;
    const bf16* vbase = vws + (size_t)kvb * S_ * D_;

    for (int kt = 0; kt < S_; kt += 64) {
        __syncthreads();
        {
            const uint4* kp = (const uint4*)(kbase + (size_t)(kt + sr) * D_ + scol);
            const uint4* vp = (const uint4*)(vbase + (size_t)(kt + sr) * D_ + scol);
            const uint4 k0 = kp[0], k1 = kp[1], v0 = vp[0], v1 = vp[1];
            float4* kd = (float4*)&sK[sr][scol];
            float4* vd = (float4*)&sV[sr][scol];
            kd[0] = make_float4(bflo(k0.x), bfhi(k0.x), bflo(k0.y), bfhi(k0.y));
            kd[1] = make_float4(bflo(k0.z), bfhi(k0.z), bflo(k0.w), bfhi(k0.w));
            kd[2] = make_float4(bflo(k1.x), bfhi(k1.x), bflo(k1.y), bfhi(k1.y));
            kd[3] = make_float4(bflo(k1.z), bfhi(k1.z), bflo(k1.w), bfhi(k1.w));
            vd[0] = make_float4(bflo(v0.x), bfhi(v0.x), bflo(v0.y), bfhi(v0.y));
            vd[1] = make_float4(bflo(v0.z), bfhi(v0.z), bflo(v0.w), bfhi(v0.w));
            vd[2] = make_float4(bflo(v1.x), bfhi(v1.x), bflo(v1.y), bfhi(v1.y));
            vd[3] = make_float4(bflo(v1.z), bfhi(v1.z), bflo(v1.w), bfhi(v1.w));
        }
        __syncthreads();

        for (int kc = 0; kc < 64; kc += 8) {
            float sc[8];
            #pragma unroll
            for (int kk = 0; kk < 8; kk++) {
                const float4* kr = (const float4*)&sK[kc + kk][0];  // broadcast
                float s0 = 0.f, s1 = 0.f, s2 = 0.f, s3 = 0.f;
                #pragma unroll
                for (int dd = 0; dd < 16; dd++) {
                    const float4 k4 = kr[dd];
                    s0 += qv[dd*4+0] * k4.x;
                    s1 += qv[dd*4+1] * k4.y;
                    s2 += qv[dd*4+2] * k4.z;
                    s3 += qv[dd*4+3] * k4.w;
                }
                sc[kk] = (s0 + s1) + (s2 + s3);
            }
            float cm = sc[0];
            #pragma unroll
            for (int kk = 1; kk < 8; kk++) cm = fmaxf(cm, sc[kk]);
            const float mnew  = fmaxf(mrun, cm);
            const float alpha = __expf(mrun - mnew);
            mrun = mnew;
            lrun *= alpha;
            #pragma unroll
            for (int d = 0; d < 64; d++) acc[d] *= alpha;
            #pragma unroll
            for (int kk = 0; kk < 8; kk++) {
                const float p = __expf(sc[kk] - mrun);
                lrun += p;
                const float4* vr = (const float4*)&sV[kc + kk][0];
                #pragma unroll
                for (int dd = 0; dd < 16; dd++) {
                    const float4 v4 = vr[dd];
                    acc[dd*4+0] += p * v4.x;
                    acc[dd*4+1] += p * v4.y;
                    acc[dd*4+2] += p * v4.z;
                    acc[dd*4+3] += p * v4.w;
                }
            }
        }
    }

    const float rl = 1.0f / lrun;
    bf16* op = ows + ((size_t)bh * S_ + qrow) * D_;
    #pragma unroll
    for (int j = 0; j < 8; j++) {
        union { uint4 v; unsigned short u[8]; } pk;
        #pragma unroll
        for (int e = 0; e < 8; e++)
            pk.u[e] = f2bfu(acc[j*8+e] * rl);
        ((uint4*)op)[j] = pk.v;
    }
}

// ---------------------------------------------------------------------------
extern "C" void kernel_launch(void* const* d_in, const int* in_sizes, int n_in,
                              void* d_out, int out_size, void* d_ws, size_t ws_size,
                              hipStream_t stream)
{
    const void*  hs  = d_in[0];               // fp32 [B,S,HID]
    const int*   pos = (const int*)d_in[1];
    const float* wq = (const float*)d_in[2];
    const float* bq = (const float*)d_in[3];
    const float* wk = (const float*)d_in[4];
    const float* bk = (const float*)d_in[5];
    const float* wv = (const float*)d_in[6];
    const float* bv = (const float*)d_in[7];
    const float* wo = (const float*)d_in[8];
    const float* bo = (const float*)d_in[9];

    // workspace layout, ~24.5 MB total:
    //   [0,256K)      ctab [S,32] fp32
    //   [256K,512K)   stab [S,32] fp32
    //   [512K,+4M)    k_ws [B,NKV,S,D] bf16
    //   [..,+4M)      v_ws [B,NKV,S,D] bf16
    //   [..,+16M)     q_ws [B,NH,S,D] bf16 (attention output written in place)
    char* ws = (char*)d_ws;
    float* ctab = (float*)(ws);
    float* stab = (float*)(ws + (256u << 10));
    bf16*  k_ws = (bf16*)(ws + (512u << 10));
    bf16*  v_ws = (bf16*)(ws + (512u << 10) + (4u << 20));
    bf16*  q_ws = (bf16*)(ws + (512u << 10) + (8u << 20));

    const int M = B_ * S_;

    rope_tab_k<<<dim3((S_ * 32 + 255) / 256), dim3(256), 0, stream>>>(pos, ctab, stab);

    gemm_k<0,1><<<dim3((NH_ * D_) / 64, M / 64), dim3(256), 0, stream>>>(
        hs, wq, bq, q_ws, M, NH_ * D_, HID_, NH_);
    gemm_k<0,1><<<dim3((NKV_ * D_) / 64, M / 64), dim3(256), 0, stream>>>(
        hs, wk, bk, k_ws, M, NKV_ * D_, HID_, NKV_);
    gemm_k<0,1><<<dim3((NKV_ * D_) / 64, M / 64), dim3(256), 0, stream>>>(
        hs, wv, bv, v_ws, M, NKV_ * D_, HID_, NKV_);

    const int rope_threads = (B_ * NH_ * S_ + B_ * NKV_ * S_) * 32;
    rope_apply_k<<<dim3((rope_threads + 255) / 256), dim3(256), 0, stream>>>(
        q_ws, k_ws, ctab, stab);

    attn_k<<<dim3(S_ / 256, B_ * NH_), dim3(256), 0, stream>>>(q_ws, k_ws, v_ws, q_ws);

    gemm_k<1,0><<<dim3(HID_ / 64, M / 64), dim3(256), 0, stream>>>(
        q_ws, wo, bo, (float*)d_out, M, HID_, NH_ * D_, 0);
}

// Round 5
// 814.842 us; speedup vs baseline: 3.2996x; 3.2996x over previous
//
#include <hip/hip_runtime.h>
#include <hip/hip_bf16.h>
#include <math.h>

#define B_   2
#define S_   2048
#define HID_ 2048
#define NH_  32
#define NKV_ 8
#define D_   64
#define G_   (NH_/NKV_)

typedef __hip_bfloat16 bf16;
typedef short bf16x8 __attribute__((ext_vector_type(8)));
typedef float f32x4  __attribute__((ext_vector_type(4)));

__device__ inline float bflo(unsigned u){ return __uint_as_float(u << 16); }
__device__ inline float bfhi(unsigned u){ return __uint_as_float(u & 0xffff0000u); }
__device__ inline unsigned short f2bfu(float f){
    __hip_bfloat16 h = __float2bfloat16(f);
    return __builtin_bit_cast(unsigned short, h);
}
__device__ inline unsigned pack2(float lo, float hi){
    return (unsigned)f2bfu(lo) | ((unsigned)f2bfu(hi) << 16);
}

// ---------------------------------------------------------------------------
// MFMA GEMM, fp32 inputs converted to bf16 in-register, bf16 MFMA compute.
// (unchanged from round 4 — passing)
// ---------------------------------------------------------------------------
template<int A_MODE, int C_MODE>
__global__ __launch_bounds__(256) void gemm_k(
    const void* __restrict__ Ax, const float* __restrict__ W,
    const float* __restrict__ bias, void* __restrict__ Cx,
    int M, int N, int K, int HC)
{
    __shared__ unsigned short sA[64][72];
    __shared__ unsigned short sB[64][72];

    const int tid  = threadIdx.x;
    const int m0   = blockIdx.y * 64;
    const int n0   = blockIdx.x * 64;
    const int wave = tid >> 6;
    const int lane = tid & 63;
    const int wm   = (wave >> 1) * 32;
    const int wn   = (wave & 1) * 32;
    const int lr   = lane & 15;
    const int lq   = lane >> 4;

    f32x4 acc[2][2];
    #pragma unroll
    for (int i = 0; i < 2; i++)
        #pragma unroll
        for (int j = 0; j < 2; j++)
            acc[i][j] = (f32x4){0.f, 0.f, 0.f, 0.f};

    const int ar = tid >> 2, ac = (tid & 3) * 16;
    const int bk = tid >> 2, bn = (tid & 3) * 16;

    for (int k0 = 0; k0 < K; k0 += 64) {
        union { uint4 q[2]; unsigned short u[16]; } av, wv;
        {
            const int m = m0 + ar;
            const int k = k0 + ac;
            if (A_MODE == 1) {
                const int b = m / S_, s = m % S_;
                const int h = k / D_, d = k % D_;
                const bf16* src = (const bf16*)Ax +
                    ((((size_t)b * NH_ + h) * S_ + s) * D_ + d);
                av.q[0] = ((const uint4*)src)[0];
                av.q[1] = ((const uint4*)src)[1];
            } else {
                const float* src = (const float*)Ax + (size_t)m * K + k;
                const float4 f0 = ((const float4*)src)[0];
                const float4 f1 = ((const float4*)src)[1];
                const float4 f2 = ((const float4*)src)[2];
                const float4 f3 = ((const float4*)src)[3];
                av.q[0] = make_uint4(pack2(f0.x,f0.y), pack2(f0.z,f0.w),
                                     pack2(f1.x,f1.y), pack2(f1.z,f1.w));
                av.q[1] = make_uint4(pack2(f2.x,f2.y), pack2(f2.z,f2.w),
                                     pack2(f3.x,f3.y), pack2(f3.z,f3.w));
            }
        }
        {
            const float* src = W + (size_t)(k0 + bk) * N + n0 + bn;
            const float4 f0 = ((const float4*)src)[0];
            const float4 f1 = ((const float4*)src)[1];
            const float4 f2 = ((const float4*)src)[2];
            const float4 f3 = ((const float4*)src)[3];
            wv.q[0] = make_uint4(pack2(f0.x,f0.y), pack2(f0.z,f0.w),
                                 pack2(f1.x,f1.y), pack2(f1.z,f1.w));
            wv.q[1] = make_uint4(pack2(f2.x,f2.y), pack2(f2.z,f2.w),
                                 pack2(f3.x,f3.y), pack2(f3.z,f3.w));
        }

        __syncthreads();

        *(uint4*)&sA[ar][ac]     = av.q[0];
        *(uint4*)&sA[ar][ac + 8] = av.q[1];
        #pragma unroll
        for (int j = 0; j < 16; j++) sB[bn + j][bk] = wv.u[j];

        __syncthreads();

        #pragma unroll
        for (int ks = 0; ks < 64; ks += 32) {
            bf16x8 af[2], bfg[2];
            #pragma unroll
            for (int mt = 0; mt < 2; mt++)
                af[mt] = *(const bf16x8*)&sA[wm + mt * 16 + lr][ks + lq * 8];
            #pragma unroll
            for (int nt = 0; nt < 2; nt++)
                bfg[nt] = *(const bf16x8*)&sB[wn + nt * 16 + lr][ks + lq * 8];
            #pragma unroll
            for (int mt = 0; mt < 2; mt++)
                #pragma unroll
                for (int nt = 0; nt < 2; nt++)
                    acc[mt][nt] = __builtin_amdgcn_mfma_f32_16x16x32_bf16(
                        af[mt], bfg[nt], acc[mt][nt], 0, 0, 0);
        }
    }

    #pragma unroll
    for (int mt = 0; mt < 2; mt++) {
        #pragma unroll
        for (int nt = 0; nt < 2; nt++) {
            #pragma unroll
            for (int r = 0; r < 4; r++) {
                const int row = m0 + wm + mt * 16 + lq * 4 + r;
                const int col = n0 + wn + nt * 16 + lr;
                const float v = acc[mt][nt][r] + bias[col];
                if (C_MODE == 0) {
                    ((float*)Cx)[(size_t)row * N + col] = v;
                } else {
                    const int b = row / S_, s = row % S_;
                    const int h = col / D_, d = col % D_;
                    ((bf16*)Cx)[(((size_t)b * HC + h) * S_ + s) * D_ + d] =
                        __float2bfloat16(v);
                }
            }
        }
    }
}

// ---------------------------------------------------------------------------
// RoPE cos/sin table (double precision); int32/int64 position_ids both handled.
// ---------------------------------------------------------------------------
__global__ __launch_bounds__(256) void rope_tab_k(
    const int* __restrict__ pos, float* __restrict__ ctab, float* __restrict__ stab)
{
    const int idx = blockIdx.x * 256 + threadIdx.x;
    if (idx >= S_ * 32) return;
    const int s = idx >> 5, i = idx & 31;
    const int is64 = (pos[1] == 0);
    const int p = is64 ? pos[2 * s] : pos[s];
    const double inv = exp(-(double)i * (log(150000.0) / 32.0));
    const double f = (double)p * inv;
    ctab[idx] = (float)cos(f);
    stab[idx] = (float)sin(f);
}

// ---------------------------------------------------------------------------
// Apply RoPE in place to q_ws [B,NH,S,D] and k_ws [B,NKV,S,D] (bf16).
// ---------------------------------------------------------------------------
__global__ __launch_bounds__(256) void rope_apply_k(
    bf16* __restrict__ q, bf16* __restrict__ k,
    const float* __restrict__ ctab, const float* __restrict__ stab)
{
    const int QP = B_ * NH_ * S_ * 32;
    const int KP = B_ * NKV_ * S_ * 32;
    const int idx = blockIdx.x * 256 + threadIdx.x;
    bf16* base; int rem;
    if (idx < QP)           { base = q; rem = idx; }
    else if (idx < QP + KP) { base = k; rem = idx - QP; }
    else return;
    const int row = rem >> 5, i = rem & 31;
    const int s = row & (S_ - 1);
    const float c  = ctab[s * 32 + i];
    const float sn = stab[s * 32 + i];
    bf16* p = base + (size_t)row * D_ + i;
    const float x1 = __bfloat162float(p[0]);
    const float x2 = __bfloat162float(p[32]);
    p[0]  = __float2bfloat16(x1 * c - x2 * sn);
    p[32] = __float2bfloat16(x2 * c + x1 * sn);
}

// ---------------------------------------------------------------------------
// MFMA flash attention (no causal mask), bf16 MFMA, fp32 accum.
// Block = 4 waves; wave owns 16 Q rows (block: 64). K-tiles of 64 keys.
// Layouts (all verified by this session's passing GEMM / guide §3):
//   A-frag: A[m=lane&15][k=(lane>>4)*8+j]   (contiguous 8 -> ds_read_b128)
//   B-frag: B[k=(lane>>4)*8+j][n=lane&15]
//   C/D:    col=lane&15, row=(lane>>4)*4+reg
// QK^T: B-operand of K^T == A-layout read of K (row-major in LDS).
// P: C-layout -> LDS (per-wave tile, same-wave DS ordering, no barrier)
//    -> re-read as A-frag for PV. V staged transposed for B-frags.
// qws/ows alias in place (block-private rows, read-before-write).
// ---------------------------------------------------------------------------
__global__ __launch_bounds__(256) void attn_k(
    const bf16* qws, const bf16* __restrict__ kws,
    const bf16* __restrict__ vws, bf16* ows)
{
    __shared__ unsigned short sK [64][72];    // [key][dim]
    __shared__ unsigned short sVt[64][72];    // [dim][key]
    __shared__ unsigned short sP [4][16][72]; // per-wave [q][key]

    const int tid  = threadIdx.x;
    const int wave = tid >> 6, lane = tid & 63;
    const int li   = lane & 15, lj = lane >> 4;
    const int bh   = blockIdx.y;
    const int q0   = blockIdx.x * 64;
    const int b    = bh / NH_, h = bh % NH_;
    const int kvb  = b * NKV_ + h / G_;

    // this wave's Q A-frags (rows q0 + wave*16 + li)
    bf16x8 qf[2];
    {
        const bf16* qp = qws + ((size_t)bh * S_ + q0 + wave * 16 + li) * D_ + lj * 8;
        qf[0] = *(const bf16x8*)(qp);
        qf[1] = *(const bf16x8*)(qp + 32);
    }

    f32x4 o[4];
    #pragma unroll
    for (int nt = 0; nt < 4; nt++) o[nt] = (f32x4){0.f, 0.f, 0.f, 0.f};
    float mr[4] = {-1e30f, -1e30f, -1e30f, -1e30f};
    float ll[4] = {0.f, 0.f, 0.f, 0.f};

    const int srow = tid >> 2, scol = (tid & 3) * 16;   // staging: key, dim base
    const bf16* kbase = kws + (size_t)kvb * S_ * D_;
    const bf16* vbase = vws + (size_t)kvb * S_ * D_;

    for (int kt = 0; kt < S_; kt += 64) {
        // ---- stage K (row-major) and V (transposed) ----
        const uint4* kp = (const uint4*)(kbase + (size_t)(kt + srow) * D_ + scol);
        const uint4* vp = (const uint4*)(vbase + (size_t)(kt + srow) * D_ + scol);
        const uint4 k0 = kp[0], k1 = kp[1];
        union { uint4 q[2]; unsigned short u[16]; } vv;
        vv.q[0] = vp[0]; vv.q[1] = vp[1];

        __syncthreads();   // prior tile's LDS reads complete
        *(uint4*)&sK[srow][scol]     = k0;
        *(uint4*)&sK[srow][scol + 8] = k1;
        #pragma unroll
        for (int e = 0; e < 16; e++) sVt[scol + e][srow] = vv.u[e];
        __syncthreads();

        // ---- QK^T: sc[nt][r] = scores for (row lj*4+r, key nt*16+li) ----
        float sc[4][4];
        #pragma unroll
        for (int nt = 0; nt < 4; nt++) {
            f32x4 c = (f32x4){0.f, 0.f, 0.f, 0.f};
            #pragma unroll
            for (int ks = 0; ks < 2; ks++) {
                const bf16x8 kf = *(const bf16x8*)&sK[nt * 16 + li][ks * 32 + lj * 8];
                c = __builtin_amdgcn_mfma_f32_16x16x32_bf16(qf[ks], kf, c, 0, 0, 0);
            }
            #pragma unroll
            for (int r = 0; r < 4; r++) sc[nt][r] = c[r] * 0.125f;
        }

        // ---- online softmax per row (shfl within 16-lane column group) ----
        #pragma unroll
        for (int r = 0; r < 4; r++) {
            float cm = fmaxf(fmaxf(sc[0][r], sc[1][r]), fmaxf(sc[2][r], sc[3][r]));
            cm = fmaxf(cm, __shfl_xor(cm, 1));
            cm = fmaxf(cm, __shfl_xor(cm, 2));
            cm = fmaxf(cm, __shfl_xor(cm, 4));
            cm = fmaxf(cm, __shfl_xor(cm, 8));
            const float mnew  = fmaxf(mr[r], cm);
            const float alpha = __expf(mr[r] - mnew);
            mr[r] = mnew;
            float rs = 0.f;
            #pragma unroll
            for (int nt = 0; nt < 4; nt++) {
                sc[nt][r] = __expf(sc[nt][r] - mnew);
                rs += sc[nt][r];
            }
            rs += __shfl_xor(rs, 1);
            rs += __shfl_xor(rs, 2);
            rs += __shfl_xor(rs, 4);
            rs += __shfl_xor(rs, 8);
            ll[r] = ll[r] * alpha + rs;
            #pragma unroll
            for (int nt = 0; nt < 4; nt++) o[nt][r] *= alpha;
        }

        // ---- P: C-layout -> per-wave LDS tile (bf16) ----
        #pragma unroll
        for (int nt = 0; nt < 4; nt++)
            #pragma unroll
            for (int r = 0; r < 4; r++)
                sP[wave][lj * 4 + r][nt * 16 + li] = f2bfu(sc[nt][r]);

        // ---- PV: A-frag from sP, B-frags from sVt ----
        #pragma unroll
        for (int ks = 0; ks < 2; ks++) {
            const bf16x8 pf = *(const bf16x8*)&sP[wave][li][ks * 32 + lj * 8];
            #pragma unroll
            for (int nt = 0; nt < 4; nt++) {
                const bf16x8 vf = *(const bf16x8*)&sVt[nt * 16 + li][ks * 32 + lj * 8];
                o[nt] = __builtin_amdgcn_mfma_f32_16x16x32_bf16(pf, vf, o[nt], 0, 0, 0);
            }
        }
    }

    // ---- epilogue: normalize, store bf16 (in place over q_ws) ----
    float inv[4];
    #pragma unroll
    for (int r = 0; r < 4; r++) inv[r] = 1.0f / ll[r];
    bf16* op = ows + ((size_t)bh * S_ + q0 + wave * 16) * D_;
    #pragma unroll
    for (int nt = 0; nt < 4; nt++)
        #pragma unroll
        for (int r = 0; r < 4; r++)
            op[(size_t)(lj * 4 + r) * D_ + nt * 16 + li] =
                __float2bfloat16(o[nt][r] * inv[r]);
}

// ---------------------------------------------------------------------------
extern "C" void kernel_launch(void* const* d_in, const int* in_sizes, int n_in,
                              void* d_out, int out_size, void* d_ws, size_t ws_size,
                              hipStream_t stream)
{
    const void*  hs  = d_in[0];               // fp32 [B,S,HID]
    const int*   pos = (const int*)d_in[1];
    const float* wq = (const float*)d_in[2];
    const float* bq = (const float*)d_in[3];
    const float* wk = (const float*)d_in[4];
    const float* bk = (const float*)d_in[5];
    const float* wv = (const float*)d_in[6];
    const float* bv = (const float*)d_in[7];
    const float* wo = (const float*)d_in[8];
    const float* bo = (const float*)d_in[9];

    // workspace: ~24.5 MB
    char* ws = (char*)d_ws;
    float* ctab = (float*)(ws);
    float* stab = (float*)(ws + (256u << 10));
    bf16*  k_ws = (bf16*)(ws + (512u << 10));
    bf16*  v_ws = (bf16*)(ws + (512u << 10) + (4u << 20));
    bf16*  q_ws = (bf16*)(ws + (512u << 10) + (8u << 20));

    const int M = B_ * S_;

    rope_tab_k<<<dim3((S_ * 32 + 255) / 256), dim3(256), 0, stream>>>(pos, ctab, stab);

    gemm_k<0,1><<<dim3((NH_ * D_) / 64, M / 64), dim3(256), 0, stream>>>(
        hs, wq, bq, q_ws, M, NH_ * D_, HID_, NH_);
    gemm_k<0,1><<<dim3((NKV_ * D_) / 64, M / 64), dim3(256), 0, stream>>>(
        hs, wk, bk, k_ws, M, NKV_ * D_, HID_, NKV_);
    gemm_k<0,1><<<dim3((NKV_ * D_) / 64, M / 64), dim3(256), 0, stream>>>(
        hs, wv, bv, v_ws, M, NKV_ * D_, HID_, NKV_);

    const int rope_threads = (B_ * NH_ * S_ + B_ * NKV_ * S_) * 32;
    rope_apply_k<<<dim3((rope_threads + 255) / 256), dim3(256), 0, stream>>>(
        q_ws, k_ws, ctab, stab);

    attn_k<<<dim3(S_ / 64, B_ * NH_), dim3(256), 0, stream>>>(q_ws, k_ws, v_ws, q_ws);

    gemm_k<1,0><<<dim3(HID_ / 64, M / 64), dim3(256), 0, stream>>>(
        q_ws, wo, bo, (float*)d_out, M, HID_, NH_ * D_, 0);
}

// Round 6
// 486.891 us; speedup vs baseline: 5.5221x; 1.6736x over previous
//
#include <hip/hip_runtime.h>
#include <hip/hip_bf16.h>
#include <math.h>

#define B_   2
#define S_   2048
#define HID_ 2048
#define NH_  32
#define NKV_ 8
#define D_   64
#define G_   (NH_/NKV_)
#define M_   (B_*S_)      // 4096

typedef __hip_bfloat16 bf16;
typedef short bf16x8 __attribute__((ext_vector_type(8)));
typedef float f32x4  __attribute__((ext_vector_type(4)));
typedef unsigned short u16x4 __attribute__((ext_vector_type(4)));

__device__ inline unsigned short f2bfu(float f){
    __hip_bfloat16 h = __float2bfloat16(f);
    return __builtin_bit_cast(unsigned short, h);
}

// async global->LDS, 16B per lane. LDS dest = wave-uniform base + lane*16.
__device__ __forceinline__ void async16(const void* g, void* l) {
    __builtin_amdgcn_global_load_lds(
        (const __attribute__((address_space(1))) unsigned int*)g,
        (__attribute__((address_space(3))) unsigned int*)l, 16, 0, 0);
}

// ---------------------------------------------------------------------------
// fp32 -> bf16 bulk convert (8 elems/thread)
// ---------------------------------------------------------------------------
__global__ __launch_bounds__(256) void cvt_k(
    const float* __restrict__ src, bf16* __restrict__ dst, int n)
{
    const int i = (blockIdx.x * 256 + threadIdx.x) * 8;
    if (i >= n) return;
    const float4 a = *(const float4*)(src + i);
    const float4 b = *(const float4*)(src + i + 4);
    uint4 u;
    u.x = (unsigned)f2bfu(a.x) | ((unsigned)f2bfu(a.y) << 16);
    u.y = (unsigned)f2bfu(a.z) | ((unsigned)f2bfu(a.w) << 16);
    u.z = (unsigned)f2bfu(b.x) | ((unsigned)f2bfu(b.y) << 16);
    u.w = (unsigned)f2bfu(b.z) | ((unsigned)f2bfu(b.w) << 16);
    *(uint4*)((unsigned short*)dst + i) = u;
}

// ---------------------------------------------------------------------------
// Transpose + convert: dst[n][k] (bf16) = src_seg[k][n] (fp32).
// Segments (wq|wk|wv) concatenated along n. 64x64 tile per block.
// ---------------------------------------------------------------------------
__global__ __launch_bounds__(256) void wtrans_k(
    const float* __restrict__ s0, int N0,
    const float* __restrict__ s1, int N1,
    const float* __restrict__ s2, int N2,
    bf16* __restrict__ dst, int K)
{
    __shared__ unsigned short t[64][65];
    const int ntile = blockIdx.x * 64, ktile = blockIdx.y * 64;
    const float* src; int nloc, Nseg;
    if (ntile < N0)           { src = s0; nloc = ntile;           Nseg = N0; }
    else if (ntile < N0 + N1) { src = s1; nloc = ntile - N0;      Nseg = N1; }
    else                      { src = s2; nloc = ntile - N0 - N1; Nseg = N2; }
    const int r  = threadIdx.x >> 4;
    const int c4 = (threadIdx.x & 15) * 4;
    #pragma unroll
    for (int p = 0; p < 4; p++) {
        const int k = p * 16 + r;
        const float4 f = *(const float4*)(src + (size_t)(ktile + k) * Nseg + nloc + c4);
        t[k][c4+0] = f2bfu(f.x); t[k][c4+1] = f2bfu(f.y);
        t[k][c4+2] = f2bfu(f.z); t[k][c4+3] = f2bfu(f.w);
    }
    __syncthreads();
    #pragma unroll
    for (int p = 0; p < 4; p++) {
        const int n = p * 16 + r;
        u16x4 u = { t[c4+0][n], t[c4+1][n], t[c4+2][n], t[c4+3][n] };
        *(u16x4*)((unsigned short*)dst + (size_t)(ntile + n) * K + ktile + c4) = u;
    }
}

// ---------------------------------------------------------------------------
// RoPE cos/sin table (double precision); int32/int64 position_ids handled.
// ---------------------------------------------------------------------------
__global__ __launch_bounds__(256) void rope_tab_k(
    const int* __restrict__ pos, float* __restrict__ ctab, float* __restrict__ stab)
{
    const int idx = blockIdx.x * 256 + threadIdx.x;
    if (idx >= S_ * 32) return;
    const int s = idx >> 5, i = idx & 31;
    const int is64 = (pos[1] == 0);
    const int p = is64 ? pos[2 * s] : pos[s];
    const double inv = exp(-(double)i * (log(150000.0) / 32.0));
    const double f = (double)p * inv;
    ctab[idx] = (float)cos(f);
    stab[idx] = (float)sin(f);
}

// ---------------------------------------------------------------------------
// m97-style MFMA GEMM: C = A[M,2048] @ WT[N,2048]^T, 128x128 tile, BK=64,
// global_load_lds staging, 4 waves, 4x4 16x16x32 frags per wave.
// MODE 0: QKV. n-segments: [0,2048) q -> Cq row-major [M][2048] (RoPE+0.125),
//               [2048,2560) k -> Ck row-major [M][512] (RoPE),
//               [2560,3072) v -> Cv transposed [B*NKV*64][S].
// MODE 1: OUT. fp32 store Cout[M][2048] + bias b0.
// ---------------------------------------------------------------------------
template<int MODE>
__global__ __launch_bounds__(256) void gemm128_k(
    const bf16* __restrict__ A, const bf16* __restrict__ WT,
    const float* __restrict__ b0, const float* __restrict__ b1,
    const float* __restrict__ b2,
    bf16* __restrict__ Cq, bf16* __restrict__ Ck, bf16* __restrict__ Cv,
    float* __restrict__ Cout,
    const float* __restrict__ ctab, const float* __restrict__ stab)
{
    __shared__ unsigned short sA[128 * 64];
    __shared__ unsigned short sB[128 * 64];

    const int tid  = threadIdx.x;
    const int wave = tid >> 6, lane = tid & 63;
    const int li   = lane & 15, lj = lane >> 4;
    const int m0   = blockIdx.y * 128;
    const int n0   = blockIdx.x * 128;
    const int wm   = (wave >> 1) * 64, wn = (wave & 1) * 64;
    const int K    = 2048;

    f32x4 acc[4][4];
    #pragma unroll
    for (int i = 0; i < 4; i++)
        #pragma unroll
        for (int j = 0; j < 4; j++)
            acc[i][j] = (f32x4){0.f, 0.f, 0.f, 0.f};

    // staging: wave w covers rows [w*32, w*32+32) of each 128x64 tile;
    // lane l: row += l>>3, col = (l&7)*8 (16B) -> lds base + l*16.
    const bf16* ag = A  + (size_t)(m0 + wave * 32 + (lane >> 3)) * K + (lane & 7) * 8;
    const bf16* bg = WT + (size_t)(n0 + wave * 32 + (lane >> 3)) * K + (lane & 7) * 8;
    unsigned short* la = &sA[(wave * 32) * 64];
    unsigned short* lb = &sB[(wave * 32) * 64];

    for (int k0 = 0; k0 < K; k0 += 64) {
        __syncthreads();   // all waves done reading previous tile
        #pragma unroll
        for (int i = 0; i < 4; i++) {
            async16(ag + k0 + (size_t)i * 8 * K, la + i * 8 * 64);
            async16(bg + k0 + (size_t)i * 8 * K, lb + i * 8 * 64);
        }
        __syncthreads();   // barrier drains vmcnt -> LDS valid

        #pragma unroll
        for (int ks = 0; ks < 64; ks += 32) {
            bf16x8 af[4], bfr[4];
            #pragma unroll
            for (int mt = 0; mt < 4; mt++)
                af[mt] = *(const bf16x8*)&sA[(wm + mt * 16 + li) * 64 + ks + lj * 8];
            #pragma unroll
            for (int nt = 0; nt < 4; nt++)
                bfr[nt] = *(const bf16x8*)&sB[(wn + nt * 16 + li) * 64 + ks + lj * 8];
            #pragma unroll
            for (int mt = 0; mt < 4; mt++)
                #pragma unroll
                for (int nt = 0; nt < 4; nt++)
                    acc[mt][nt] = __builtin_amdgcn_mfma_f32_16x16x32_bf16(
                        af[mt], bfr[nt], acc[mt][nt], 0, 0, 0);
        }
    }

    // ---- epilogue (C/D: col=li, row=lj*4+r) ----
    if (MODE == 1) {
        #pragma unroll
        for (int mt = 0; mt < 4; mt++)
            #pragma unroll
            for (int nt = 0; nt < 4; nt++) {
                const int col = n0 + wn + nt * 16 + li;
                const float bb = b0[col];
                #pragma unroll
                for (int r = 0; r < 4; r++) {
                    const int row = m0 + wm + mt * 16 + lj * 4 + r;
                    Cout[(size_t)row * HID_ + col] = acc[mt][nt][r] + bb;
                }
            }
        return;
    }

    int seg, cb; const float* bias;
    if (n0 < 2048)      { seg = 0; cb = n0;        bias = b0; }
    else if (n0 < 2560) { seg = 1; cb = n0 - 2048; bias = b1; }
    else                { seg = 2; cb = n0 - 2560; bias = b2; }

    float bl[4];
    #pragma unroll
    for (int nt = 0; nt < 4; nt++) bl[nt] = bias[cb + wn + nt * 16 + li];

    if (seg == 2) {
        // V: store transposed [B*NKV*64 (=b,h,d)][S], 4 consecutive s per store
        const int b = m0 >> 11;
        #pragma unroll
        for (int nt = 0; nt < 4; nt++) {
            const int cseg = cb + wn + nt * 16 + li;   // 0..511
            const int hv = cseg >> 6, d = cseg & 63;
            #pragma unroll
            for (int mt = 0; mt < 4; mt++) {
                const int sb = (m0 & (S_ - 1)) + wm + mt * 16 + lj * 4;
                u16x4 u = { f2bfu(acc[mt][nt][0] + bl[nt]),
                            f2bfu(acc[mt][nt][1] + bl[nt]),
                            f2bfu(acc[mt][nt][2] + bl[nt]),
                            f2bfu(acc[mt][nt][3] + bl[nt]) };
                *(u16x4*)((unsigned short*)Cv +
                    ((size_t)((b * NKV_ + hv) * 64 + d)) * S_ + sb) = u;
            }
        }
        return;
    }

    // Q/K: fused RoPE in fp32. Lane cols within one head: d = nt*16+li,
    // pairs (nt,nt+2) are (d, d+32). Q also folds the 1/sqrt(D) scale.
    const float qs = (seg == 0) ? 0.125f : 1.0f;
    #pragma unroll
    for (int mt = 0; mt < 4; mt++) {
        #pragma unroll
        for (int r = 0; r < 4; r++) {
            const int row = m0 + wm + mt * 16 + lj * 4 + r;
            const int s = row & (S_ - 1);
            const float c0  = ctab[s * 32 + li],      sn0 = stab[s * 32 + li];
            const float c1  = ctab[s * 32 + 16 + li], sn1 = stab[s * 32 + 16 + li];
            const float x0 = acc[mt][0][r] + bl[0];
            const float x1 = acc[mt][1][r] + bl[1];
            const float x2 = acc[mt][2][r] + bl[2];
            const float x3 = acc[mt][3][r] + bl[3];
            const float y0 = (x0 * c0 - x2 * sn0) * qs;
            const float y2 = (x2 * c0 + x0 * sn0) * qs;
            const float y1 = (x1 * c1 - x3 * sn1) * qs;
            const float y3 = (x3 * c1 + x1 * sn1) * qs;
            if (seg == 0) {
                bf16* cp = Cq + (size_t)row * HID_ + n0 + wn + li;
                cp[0]  = __float2bfloat16(y0);
                cp[16] = __float2bfloat16(y1);
                cp[32] = __float2bfloat16(y2);
                cp[48] = __float2bfloat16(y3);
            } else {
                bf16* cp = Ck + (size_t)row * 512 + cb + wn + li;
                cp[0]  = __float2bfloat16(y0);
                cp[16] = __float2bfloat16(y1);
                cp[32] = __float2bfloat16(y2);
                cp[48] = __float2bfloat16(y3);
            }
        }
    }
}

// ---------------------------------------------------------------------------
// MFMA flash attention. Q row-major [M][2048] (pre-scaled), K row-major
// [M][512], V transposed [B*NKV*64][S]. Output row-major [M][2048].
// Block = 4 waves, 64 Q rows; K-tiles of 64 keys.
// ---------------------------------------------------------------------------
__global__ __launch_bounds__(256) void attn_k(
    const bf16* __restrict__ qws, const bf16* __restrict__ kws,
    const bf16* __restrict__ vtw, bf16* __restrict__ ows)
{
    __shared__ unsigned short sK [64][72];    // [key][dim]
    __shared__ unsigned short sVt[64][72];    // [dim][key]
    __shared__ unsigned short sP [4][16][72]; // per-wave [q][key]

    const int tid  = threadIdx.x;
    const int wave = tid >> 6, lane = tid & 63;
    const int li   = lane & 15, lj = lane >> 4;
    const int bh   = blockIdx.y;
    const int q0   = blockIdx.x * 64;
    const int b    = bh / NH_, h = bh % NH_;
    const int hk   = h / G_;

    bf16x8 qf[2];
    {
        const bf16* qp = qws + (size_t)(b * S_ + q0 + wave * 16 + li) * HID_
                         + h * D_ + lj * 8;
        qf[0] = *(const bf16x8*)(qp);
        qf[1] = *(const bf16x8*)(qp + 32);
    }

    f32x4 o[4];
    #pragma unroll
    for (int nt = 0; nt < 4; nt++) o[nt] = (f32x4){0.f, 0.f, 0.f, 0.f};
    float mr[4] = {-1e30f, -1e30f, -1e30f, -1e30f};
    float ll[4] = {0.f, 0.f, 0.f, 0.f};

    const int srow = tid >> 2, scol = (tid & 3) * 16;
    const bf16* kb = kws + (size_t)b * S_ * 512 + hk * 64;
    const bf16* vb = vtw + (size_t)((b * NKV_ + hk) * 64) * S_;

    for (int kt = 0; kt < S_; kt += 64) {
        const uint4* kp = (const uint4*)(kb + (size_t)(kt + srow) * 512 + scol);
        const uint4* vp = (const uint4*)(vb + (size_t)srow * S_ + kt + scol);
        const uint4 k0 = kp[0], k1 = kp[1];
        const uint4 v0 = vp[0], v1 = vp[1];

        __syncthreads();
        *(uint4*)&sK [srow][scol]     = k0;
        *(uint4*)&sK [srow][scol + 8] = k1;
        *(uint4*)&sVt[srow][scol]     = v0;
        *(uint4*)&sVt[srow][scol + 8] = v1;
        __syncthreads();

        // QK^T (Q pre-scaled by 1/8)
        float sc[4][4];
        #pragma unroll
        for (int nt = 0; nt < 4; nt++) {
            f32x4 c = (f32x4){0.f, 0.f, 0.f, 0.f};
            #pragma unroll
            for (int ks = 0; ks < 2; ks++) {
                const bf16x8 kf = *(const bf16x8*)&sK[nt * 16 + li][ks * 32 + lj * 8];
                c = __builtin_amdgcn_mfma_f32_16x16x32_bf16(qf[ks], kf, c, 0, 0, 0);
            }
            #pragma unroll
            for (int r = 0; r < 4; r++) sc[nt][r] = c[r];
        }

        // online softmax per row
        #pragma unroll
        for (int r = 0; r < 4; r++) {
            float cm = fmaxf(fmaxf(sc[0][r], sc[1][r]), fmaxf(sc[2][r], sc[3][r]));
            cm = fmaxf(cm, __shfl_xor(cm, 1));
            cm = fmaxf(cm, __shfl_xor(cm, 2));
            cm = fmaxf(cm, __shfl_xor(cm, 4));
            cm = fmaxf(cm, __shfl_xor(cm, 8));
            const float mnew  = fmaxf(mr[r], cm);
            const float alpha = __expf(mr[r] - mnew);
            mr[r] = mnew;
            float rs = 0.f;
            #pragma unroll
            for (int nt = 0; nt < 4; nt++) {
                sc[nt][r] = __expf(sc[nt][r] - mnew);
                rs += sc[nt][r];
            }
            rs += __shfl_xor(rs, 1);
            rs += __shfl_xor(rs, 2);
            rs += __shfl_xor(rs, 4);
            rs += __shfl_xor(rs, 8);
            ll[r] = ll[r] * alpha + rs;
            #pragma unroll
            for (int nt = 0; nt < 4; nt++) o[nt][r] *= alpha;
        }

        // P: C-layout -> per-wave LDS tile
        #pragma unroll
        for (int nt = 0; nt < 4; nt++)
            #pragma unroll
            for (int r = 0; r < 4; r++)
                sP[wave][lj * 4 + r][nt * 16 + li] = f2bfu(sc[nt][r]);

        // PV
        #pragma unroll
        for (int ks = 0; ks < 2; ks++) {
            const bf16x8 pf = *(const bf16x8*)&sP[wave][li][ks * 32 + lj * 8];
            #pragma unroll
            for (int nt = 0; nt < 4; nt++) {
                const bf16x8 vf = *(const bf16x8*)&sVt[nt * 16 + li][ks * 32 + lj * 8];
                o[nt] = __builtin_amdgcn_mfma_f32_16x16x32_bf16(pf, vf, o[nt], 0, 0, 0);
            }
        }
    }

    float inv[4];
    #pragma unroll
    for (int r = 0; r < 4; r++) inv[r] = 1.0f / ll[r];
    bf16* op = ows + (size_t)(b * S_ + q0 + wave * 16) * HID_ + h * D_;
    #pragma unroll
    for (int nt = 0; nt < 4; nt++)
        #pragma unroll
        for (int r = 0; r < 4; r++)
            op[(size_t)(lj * 4 + r) * HID_ + nt * 16 + li] =
                __float2bfloat16(o[nt][r] * inv[r]);
}

// ---------------------------------------------------------------------------
extern "C" void kernel_launch(void* const* d_in, const int* in_sizes, int n_in,
                              void* d_out, int out_size, void* d_ws, size_t ws_size,
                              hipStream_t stream)
{
    const float* hs  = (const float*)d_in[0];
    const int*   pos = (const int*)d_in[1];
    const float* wq = (const float*)d_in[2];
    const float* bq = (const float*)d_in[3];
    const float* wk = (const float*)d_in[4];
    const float* bk = (const float*)d_in[5];
    const float* wv = (const float*)d_in[6];
    const float* bv = (const float*)d_in[7];
    const float* wo = (const float*)d_in[8];
    const float* bo = (const float*)d_in[9];

    // workspace (52.5 MB peak):
    //   [0,256K)   ctab          [256K,512K) stab
    //   +0.5M: k_ws  [4096][512] bf16   (4 MB)
    //   +4.5M: v_t   [B*NKV*64][S] bf16 (4 MB)
    //   +8.5M: q_ws  [4096][2048] bf16 (16 MB)   (woT overlays after attn)
    //   +24.5M: hs_b [4096][2048] bf16 (16 MB)   (o_ws overlays after QKV gemm)
    //   +40.5M: wqkvT [3072][2048] bf16 (12 MB)
    char* ws = (char*)d_ws;
    float* ctab  = (float*)(ws);
    float* stab  = (float*)(ws + (256u << 10));
    bf16*  k_ws  = (bf16*)(ws + (512u << 10));
    bf16*  v_t   = (bf16*)(ws + (512u << 10) + (4u  << 20));
    bf16*  q_ws  = (bf16*)(ws + (512u << 10) + (8u  << 20));
    bf16*  woT   = q_ws;                                   // overlay
    bf16*  hs_b  = (bf16*)(ws + (512u << 10) + (24u << 20));
    bf16*  o_ws  = hs_b;                                   // overlay
    bf16*  wqkvT = (bf16*)(ws + (512u << 10) + (40u << 20));

    rope_tab_k<<<dim3(256), dim3(256), 0, stream>>>(pos, ctab, stab);

    cvt_k<<<dim3(M_ * HID_ / 2048), dim3(256), 0, stream>>>(hs, hs_b, M_ * HID_);

    wtrans_k<<<dim3(48, 32), dim3(256), 0, stream>>>(
        wq, 2048, wk, 512, wv, 512, wqkvT, HID_);

    gemm128_k<0><<<dim3(24, 32), dim3(256), 0, stream>>>(
        hs_b, wqkvT, bq, bk, bv, q_ws, k_ws, v_t, nullptr, ctab, stab);

    attn_k<<<dim3(S_ / 64, B_ * NH_), dim3(256), 0, stream>>>(q_ws, k_ws, v_t, o_ws);

    wtrans_k<<<dim3(32, 32), dim3(256), 0, stream>>>(
        wo, 2048, wo, 0, wo, 0, woT, HID_);

    gemm128_k<1><<<dim3(16, 32), dim3(256), 0, stream>>>(
        o_ws, woT, bo, nullptr, nullptr, nullptr, nullptr, nullptr,
        (float*)d_out, nullptr, nullptr);
}

// Round 7
// 401.621 us; speedup vs baseline: 6.6945x; 1.2123x over previous
//
#include <hip/hip_runtime.h>
#include <hip/hip_bf16.h>
#include <math.h>

#define B_   2
#define S_   2048
#define HID_ 2048
#define NH_  32
#define NKV_ 8
#define D_   64
#define G_   (NH_/NKV_)
#define M_   (B_*S_)      // 4096

typedef __hip_bfloat16 bf16;
typedef short bf16x8 __attribute__((ext_vector_type(8)));
typedef float f32x4  __attribute__((ext_vector_type(4)));
typedef unsigned short u16x4 __attribute__((ext_vector_type(4)));

__device__ inline unsigned short f2bfu(float f){
    __hip_bfloat16 h = __float2bfloat16(f);
    return __builtin_bit_cast(unsigned short, h);
}

__device__ __forceinline__ float fexp2(float x){
#if __has_builtin(__builtin_amdgcn_exp2f)
    return __builtin_amdgcn_exp2f(x);
#else
    return exp2f(x);
#endif
}

// async global->LDS, 16B per lane. LDS dest = wave-uniform base + lane*16.
__device__ __forceinline__ void async16(const void* g, void* l) {
    __builtin_amdgcn_global_load_lds(
        (const __attribute__((address_space(1))) unsigned int*)g,
        (__attribute__((address_space(3))) unsigned int*)l, 16, 0, 0);
}

// ---------------------------------------------------------------------------
// fp32 -> bf16 bulk convert (8 elems/thread)
// ---------------------------------------------------------------------------
__global__ __launch_bounds__(256) void cvt_k(
    const float* __restrict__ src, bf16* __restrict__ dst, int n)
{
    const int i = (blockIdx.x * 256 + threadIdx.x) * 8;
    if (i >= n) return;
    const float4 a = *(const float4*)(src + i);
    const float4 b = *(const float4*)(src + i + 4);
    uint4 u;
    u.x = (unsigned)f2bfu(a.x) | ((unsigned)f2bfu(a.y) << 16);
    u.y = (unsigned)f2bfu(a.z) | ((unsigned)f2bfu(a.w) << 16);
    u.z = (unsigned)f2bfu(b.x) | ((unsigned)f2bfu(b.y) << 16);
    u.w = (unsigned)f2bfu(b.z) | ((unsigned)f2bfu(b.w) << 16);
    *(uint4*)((unsigned short*)dst + i) = u;
}

// ---------------------------------------------------------------------------
// Transpose + convert: dst[n][k] (bf16) = src_seg[k][n] (fp32).
// ---------------------------------------------------------------------------
__global__ __launch_bounds__(256) void wtrans_k(
    const float* __restrict__ s0, int N0,
    const float* __restrict__ s1, int N1,
    const float* __restrict__ s2, int N2,
    bf16* __restrict__ dst, int K)
{
    __shared__ unsigned short t[64][65];
    const int ntile = blockIdx.x * 64, ktile = blockIdx.y * 64;
    const float* src; int nloc, Nseg;
    if (ntile < N0)           { src = s0; nloc = ntile;           Nseg = N0; }
    else if (ntile < N0 + N1) { src = s1; nloc = ntile - N0;      Nseg = N1; }
    else                      { src = s2; nloc = ntile - N0 - N1; Nseg = N2; }
    const int r  = threadIdx.x >> 4;
    const int c4 = (threadIdx.x & 15) * 4;
    #pragma unroll
    for (int p = 0; p < 4; p++) {
        const int k = p * 16 + r;
        const float4 f = *(const float4*)(src + (size_t)(ktile + k) * Nseg + nloc + c4);
        t[k][c4+0] = f2bfu(f.x); t[k][c4+1] = f2bfu(f.y);
        t[k][c4+2] = f2bfu(f.z); t[k][c4+3] = f2bfu(f.w);
    }
    __syncthreads();
    #pragma unroll
    for (int p = 0; p < 4; p++) {
        const int n = p * 16 + r;
        u16x4 u = { t[c4+0][n], t[c4+1][n], t[c4+2][n], t[c4+3][n] };
        *(u16x4*)((unsigned short*)dst + (size_t)(ntile + n) * K + ktile + c4) = u;
    }
}

// ---------------------------------------------------------------------------
// RoPE cos/sin table (double precision); int32/int64 position_ids handled.
// ---------------------------------------------------------------------------
__global__ __launch_bounds__(256) void rope_tab_k(
    const int* __restrict__ pos, float* __restrict__ ctab, float* __restrict__ stab)
{
    const int idx = blockIdx.x * 256 + threadIdx.x;
    if (idx >= S_ * 32) return;
    const int s = idx >> 5, i = idx & 31;
    const int is64 = (pos[1] == 0);
    const int p = is64 ? pos[2 * s] : pos[s];
    const double inv = exp(-(double)i * (log(150000.0) / 32.0));
    const double f = (double)p * inv;
    ctab[idx] = (float)cos(f);
    stab[idx] = (float)sin(f);
}

// ---------------------------------------------------------------------------
// m97-style MFMA GEMM: C = A[M,2048] @ WT[N,2048]^T, 128x128 tile, BK=64.
// MODE 0: QKV (Q gets RoPE + 0.125*log2e scale -> exp2-domain attention;
//              K gets RoPE; V stored transposed [B*NKV*64][S]).
// MODE 1: OUT (fp32 store + bias b0).
// ---------------------------------------------------------------------------
template<int MODE>
__global__ __launch_bounds__(256) void gemm128_k(
    const bf16* __restrict__ A, const bf16* __restrict__ WT,
    const float* __restrict__ b0, const float* __restrict__ b1,
    const float* __restrict__ b2,
    bf16* __restrict__ Cq, bf16* __restrict__ Ck, bf16* __restrict__ Cv,
    float* __restrict__ Cout,
    const float* __restrict__ ctab, const float* __restrict__ stab)
{
    __shared__ unsigned short sA[128 * 64];
    __shared__ unsigned short sB[128 * 64];

    const int tid  = threadIdx.x;
    const int wave = tid >> 6, lane = tid & 63;
    const int li   = lane & 15, lj = lane >> 4;
    const int m0   = blockIdx.y * 128;
    const int n0   = blockIdx.x * 128;
    const int wm   = (wave >> 1) * 64, wn = (wave & 1) * 64;
    const int K    = 2048;

    f32x4 acc[4][4];
    #pragma unroll
    for (int i = 0; i < 4; i++)
        #pragma unroll
        for (int j = 0; j < 4; j++)
            acc[i][j] = (f32x4){0.f, 0.f, 0.f, 0.f};

    const bf16* ag = A  + (size_t)(m0 + wave * 32 + (lane >> 3)) * K + (lane & 7) * 8;
    const bf16* bg = WT + (size_t)(n0 + wave * 32 + (lane >> 3)) * K + (lane & 7) * 8;
    unsigned short* la = &sA[(wave * 32) * 64];
    unsigned short* lb = &sB[(wave * 32) * 64];

    for (int k0 = 0; k0 < K; k0 += 64) {
        __syncthreads();
        #pragma unroll
        for (int i = 0; i < 4; i++) {
            async16(ag + k0 + (size_t)i * 8 * K, la + i * 8 * 64);
            async16(bg + k0 + (size_t)i * 8 * K, lb + i * 8 * 64);
        }
        __syncthreads();

        #pragma unroll
        for (int ks = 0; ks < 64; ks += 32) {
            bf16x8 af[4], bfr[4];
            #pragma unroll
            for (int mt = 0; mt < 4; mt++)
                af[mt] = *(const bf16x8*)&sA[(wm + mt * 16 + li) * 64 + ks + lj * 8];
            #pragma unroll
            for (int nt = 0; nt < 4; nt++)
                bfr[nt] = *(const bf16x8*)&sB[(wn + nt * 16 + li) * 64 + ks + lj * 8];
            #pragma unroll
            for (int mt = 0; mt < 4; mt++)
                #pragma unroll
                for (int nt = 0; nt < 4; nt++)
                    acc[mt][nt] = __builtin_amdgcn_mfma_f32_16x16x32_bf16(
                        af[mt], bfr[nt], acc[mt][nt], 0, 0, 0);
        }
    }

    if (MODE == 1) {
        #pragma unroll
        for (int mt = 0; mt < 4; mt++)
            #pragma unroll
            for (int nt = 0; nt < 4; nt++) {
                const int col = n0 + wn + nt * 16 + li;
                const float bb = b0[col];
                #pragma unroll
                for (int r = 0; r < 4; r++) {
                    const int row = m0 + wm + mt * 16 + lj * 4 + r;
                    Cout[(size_t)row * HID_ + col] = acc[mt][nt][r] + bb;
                }
            }
        return;
    }

    int seg, cb; const float* bias;
    if (n0 < 2048)      { seg = 0; cb = n0;        bias = b0; }
    else if (n0 < 2560) { seg = 1; cb = n0 - 2048; bias = b1; }
    else                { seg = 2; cb = n0 - 2560; bias = b2; }

    float bl[4];
    #pragma unroll
    for (int nt = 0; nt < 4; nt++) bl[nt] = bias[cb + wn + nt * 16 + li];

    if (seg == 2) {
        const int b = m0 >> 11;
        #pragma unroll
        for (int nt = 0; nt < 4; nt++) {
            const int cseg = cb + wn + nt * 16 + li;
            const int hv = cseg >> 6, d = cseg & 63;
            #pragma unroll
            for (int mt = 0; mt < 4; mt++) {
                const int sb = (m0 & (S_ - 1)) + wm + mt * 16 + lj * 4;
                u16x4 u = { f2bfu(acc[mt][nt][0] + bl[nt]),
                            f2bfu(acc[mt][nt][1] + bl[nt]),
                            f2bfu(acc[mt][nt][2] + bl[nt]),
                            f2bfu(acc[mt][nt][3] + bl[nt]) };
                *(u16x4*)((unsigned short*)Cv +
                    ((size_t)((b * NKV_ + hv) * 64 + d)) * S_ + sb) = u;
            }
        }
        return;
    }

    // Q/K: fused RoPE. Q also folds 0.125 * log2(e) (exp2-domain softmax).
    const float qs = (seg == 0) ? 0.18033688011112042f : 1.0f;
    #pragma unroll
    for (int mt = 0; mt < 4; mt++) {
        #pragma unroll
        for (int r = 0; r < 4; r++) {
            const int row = m0 + wm + mt * 16 + lj * 4 + r;
            const int s = row & (S_ - 1);
            const float c0  = ctab[s * 32 + li],      sn0 = stab[s * 32 + li];
            const float c1  = ctab[s * 32 + 16 + li], sn1 = stab[s * 32 + 16 + li];
            const float x0 = acc[mt][0][r] + bl[0];
            const float x1 = acc[mt][1][r] + bl[1];
            const float x2 = acc[mt][2][r] + bl[2];
            const float x3 = acc[mt][3][r] + bl[3];
            const float y0 = (x0 * c0 - x2 * sn0) * qs;
            const float y2 = (x2 * c0 + x0 * sn0) * qs;
            const float y1 = (x1 * c1 - x3 * sn1) * qs;
            const float y3 = (x3 * c1 + x1 * sn1) * qs;
            if (seg == 0) {
                bf16* cp = Cq + (size_t)row * HID_ + n0 + wn + li;
                cp[0]  = __float2bfloat16(y0);
                cp[16] = __float2bfloat16(y1);
                cp[32] = __float2bfloat16(y2);
                cp[48] = __float2bfloat16(y3);
            } else {
                bf16* cp = Ck + (size_t)row * 512 + cb + wn + li;
                cp[0]  = __float2bfloat16(y0);
                cp[16] = __float2bfloat16(y1);
                cp[32] = __float2bfloat16(y2);
                cp[48] = __float2bfloat16(y3);
            }
        }
    }
}

// ---------------------------------------------------------------------------
// MFMA flash attention, TRANSPOSED scores: St = K @ Q^T (swap MFMA operands,
// same register contents). Lane (li=q, lj) holds 16 scores of q-row li ->
// softmax reductions mostly in-lane (2 shfl instead of 16). exp2 domain
// (Q pre-scaled by 0.125*log2e). P stored [q][key] (4x ds_write_b64),
// read back as B-operand of O^T = V^T @ P^T; V^T A-frags from sVt.
// O^T C-layout: lane holds O[q=li][dim=mt*16+lj*4+r] -> 4x 8B stores.
// ---------------------------------------------------------------------------
__global__ __launch_bounds__(256) void attn_k(
    const bf16* __restrict__ qws, const bf16* __restrict__ kws,
    const bf16* __restrict__ vtw, bf16* __restrict__ ows)
{
    __shared__ unsigned short sK [64][72];    // [key][dim]
    __shared__ unsigned short sVt[64][72];    // [dim][key]
    __shared__ unsigned short sP [4][16][72]; // per-wave [q][key]

    const int tid  = threadIdx.x;
    const int wave = tid >> 6, lane = tid & 63;
    const int li   = lane & 15, lj = lane >> 4;
    const int bh   = blockIdx.y;
    const int q0   = blockIdx.x * 64;
    const int b    = bh / NH_, h = bh % NH_;
    const int hk   = h / G_;

    bf16x8 qf[2];
    {
        const bf16* qp = qws + (size_t)(b * S_ + q0 + wave * 16 + li) * HID_
                         + h * D_ + lj * 8;
        qf[0] = *(const bf16x8*)(qp);
        qf[1] = *(const bf16x8*)(qp + 32);
    }

    f32x4 o[4];
    #pragma unroll
    for (int mt = 0; mt < 4; mt++) o[mt] = (f32x4){0.f, 0.f, 0.f, 0.f};
    float mr = -1e30f, ll = 0.f;

    const int srow = tid >> 2, scol = (tid & 3) * 16;
    const bf16* kb = kws + (size_t)b * S_ * 512 + hk * 64;
    const bf16* vb = vtw + (size_t)((b * NKV_ + hk) * 64) * S_;

    for (int kt = 0; kt < S_; kt += 64) {
        const uint4* kp = (const uint4*)(kb + (size_t)(kt + srow) * 512 + scol);
        const uint4* vp = (const uint4*)(vb + (size_t)srow * S_ + kt + scol);
        const uint4 k0 = kp[0], k1 = kp[1];
        const uint4 v0 = vp[0], v1 = vp[1];

        __syncthreads();
        *(uint4*)&sK [srow][scol]     = k0;
        *(uint4*)&sK [srow][scol + 8] = k1;
        *(uint4*)&sVt[srow][scol]     = v0;
        *(uint4*)&sVt[srow][scol + 8] = v1;
        __syncthreads();

        // St = K·Q^T: lane holds score(q=li, key=kt + nt*16 + lj*4 + r)
        float sc[4][4];
        #pragma unroll
        for (int nt = 0; nt < 4; nt++) {
            f32x4 c = (f32x4){0.f, 0.f, 0.f, 0.f};
            #pragma unroll
            for (int ks = 0; ks < 2; ks++) {
                const bf16x8 kf = *(const bf16x8*)&sK[nt * 16 + li][ks * 32 + lj * 8];
                c = __builtin_amdgcn_mfma_f32_16x16x32_bf16(kf, qf[ks], c, 0, 0, 0);
            }
            #pragma unroll
            for (int r = 0; r < 4; r++) sc[nt][r] = c[r];
        }

        // online softmax for q-row li (redundant across the 4 lj lanes)
        float cm = sc[0][0];
        #pragma unroll
        for (int nt = 0; nt < 4; nt++)
            #pragma unroll
            for (int r = 0; r < 4; r++) cm = fmaxf(cm, sc[nt][r]);
        cm = fmaxf(cm, __shfl_xor(cm, 16));
        cm = fmaxf(cm, __shfl_xor(cm, 32));
        const float mnew  = fmaxf(mr, cm);
        const float alpha = fexp2(mr - mnew);
        mr = mnew;
        float rs = 0.f;
        #pragma unroll
        for (int nt = 0; nt < 4; nt++)
            #pragma unroll
            for (int r = 0; r < 4; r++) {
                sc[nt][r] = fexp2(sc[nt][r] - mnew);
                rs += sc[nt][r];
            }
        rs += __shfl_xor(rs, 16);
        rs += __shfl_xor(rs, 32);
        ll = ll * alpha + rs;
        #pragma unroll
        for (int mt = 0; mt < 4; mt++) o[mt] *= alpha;

        // P -> sP[q][key], 4 consecutive keys per write (b64)
        #pragma unroll
        for (int nt = 0; nt < 4; nt++) {
            u16x4 u = { f2bfu(sc[nt][0]), f2bfu(sc[nt][1]),
                        f2bfu(sc[nt][2]), f2bfu(sc[nt][3]) };
            *(u16x4*)&sP[wave][li][nt * 16 + lj * 4] = u;
        }

        // O^T = V^T·P^T: A-frag from sVt (dim-major), B-frag from sP
        #pragma unroll
        for (int ks = 0; ks < 2; ks++) {
            const bf16x8 pf = *(const bf16x8*)&sP[wave][li][ks * 32 + lj * 8];
            #pragma unroll
            for (int mt = 0; mt < 4; mt++) {
                const bf16x8 vf = *(const bf16x8*)&sVt[mt * 16 + li][ks * 32 + lj * 8];
                o[mt] = __builtin_amdgcn_mfma_f32_16x16x32_bf16(vf, pf, o[mt], 0, 0, 0);
            }
        }
    }

    // epilogue: lane holds O[q=li][dim=mt*16+lj*4+r]
    const float inv = 1.0f / ll;
    bf16* op = ows + (size_t)(b * S_ + q0 + wave * 16 + li) * HID_ + h * D_;
    #pragma unroll
    for (int mt = 0; mt < 4; mt++) {
        u16x4 u = { f2bfu(o[mt][0] * inv), f2bfu(o[mt][1] * inv),
                    f2bfu(o[mt][2] * inv), f2bfu(o[mt][3] * inv) };
        *(u16x4*)((unsigned short*)op + mt * 16 + lj * 4) = u;
    }
}

// ---------------------------------------------------------------------------
extern "C" void kernel_launch(void* const* d_in, const int* in_sizes, int n_in,
                              void* d_out, int out_size, void* d_ws, size_t ws_size,
                              hipStream_t stream)
{
    const float* hs  = (const float*)d_in[0];
    const int*   pos = (const int*)d_in[1];
    const float* wq = (const float*)d_in[2];
    const float* bq = (const float*)d_in[3];
    const float* wk = (const float*)d_in[4];
    const float* bk = (const float*)d_in[5];
    const float* wv = (const float*)d_in[6];
    const float* bv = (const float*)d_in[7];
    const float* wo = (const float*)d_in[8];
    const float* bo = (const float*)d_in[9];

    // workspace (52.5 MB peak)
    char* ws = (char*)d_ws;
    float* ctab  = (float*)(ws);
    float* stab  = (float*)(ws + (256u << 10));
    bf16*  k_ws  = (bf16*)(ws + (512u << 10));
    bf16*  v_t   = (bf16*)(ws + (512u << 10) + (4u  << 20));
    bf16*  q_ws  = (bf16*)(ws + (512u << 10) + (8u  << 20));
    bf16*  woT   = q_ws;                                   // overlay
    bf16*  hs_b  = (bf16*)(ws + (512u << 10) + (24u << 20));
    bf16*  o_ws  = hs_b;                                   // overlay
    bf16*  wqkvT = (bf16*)(ws + (512u << 10) + (40u << 20));

    rope_tab_k<<<dim3(256), dim3(256), 0, stream>>>(pos, ctab, stab);

    cvt_k<<<dim3(M_ * HID_ / 2048), dim3(256), 0, stream>>>(hs, hs_b, M_ * HID_);

    wtrans_k<<<dim3(48, 32), dim3(256), 0, stream>>>(
        wq, 2048, wk, 512, wv, 512, wqkvT, HID_);

    gemm128_k<0><<<dim3(24, 32), dim3(256), 0, stream>>>(
        hs_b, wqkvT, bq, bk, bv, q_ws, k_ws, v_t, nullptr, ctab, stab);

    attn_k<<<dim3(S_ / 64, B_ * NH_), dim3(256), 0, stream>>>(q_ws, k_ws, v_t, o_ws);

    wtrans_k<<<dim3(32, 32), dim3(256), 0, stream>>>(
        wo, 2048, wo, 0, wo, 0, woT, HID_);

    gemm128_k<1><<<dim3(16, 32), dim3(256), 0, stream>>>(
        o_ws, woT, bo, nullptr, nullptr, nullptr, nullptr, nullptr,
        (float*)d_out, nullptr, nullptr);
}